// Round 13
// baseline (181.273 us; speedup 1.0000x reference)
//
#include <hip/hip_runtime.h>
#include <hip/hip_bf16.h>
#include <math.h>

typedef __hip_bfloat16 bf16;
__device__ __forceinline__ float b2f(bf16 v){ return __bfloat162float(v); }

#define SEQL 256
#define FEAT 64
#define NC 99
#define KS 15

// workspace layout in floats (~29.5 MB incl. bf16 act)
#define OFF_MU    0          // 4096    (b,i,f)
#define OFF_RSTD  4096       // 4096
#define OFF_EN    8192       // 512     (b,i,j)  atomic-summed energy
#define OFF_RS    9728       // 16384   (b,i,s)  sum_f proj
#define OFF_R2    26112      // 16384   (b,i,s)  sum_f proj^2
#define OFF_COMB  42496      // 1048576 (b,j,s,f) f32
#define OFF_D     1091072    // 2097152 (b,i2,s,t) f32  j-independent QK dots
#define OFF_ACT   3188224    // 8388608 bf16 slots (b,i,j,s,f)

#define OUT1_OFF  1048576    // projs (x_prime) region start in d_out (f32)

// -------- kernel 1: stats only (64 blocks -> ~5us, shortens critical path) --
__global__ void __launch_bounds__(256)
k_stats(const float* __restrict__ x_in, float* __restrict__ ws){
    int bi = blockIdx.x;
    int t = threadIdx.x;
    int f = t & 63, q = t >> 6;
    const float* xp = x_in + (size_t)bi * SEQL * FEAT;
    float s = 0.f, ss = 0.f;
    for (int k = 0; k < 64; ++k) {
        float v = xp[(q*64 + k) * FEAT + f];
        s += v; ss += v * v;
    }
    __shared__ float ls[256], lss[256];
    ls[t] = s; lss[t] = ss;
    __syncthreads();
    if (q == 0) {
        float S  = ls[f]  + ls[64+f]  + ls[128+f]  + ls[192+f];
        float SS = lss[f] + lss[64+f] + lss[128+f] + lss[192+f];
        float m = S * (1.f/256.f);
        float var = SS * (1.f/256.f) - m * m;
        ws[OFF_MU   + bi*64 + f] = m;
        ws[OFF_RSTD + bi*64 + f] = rsqrtf(var + 1e-5f);
    }
    if (bi == 0) {
        for (int k = t; k < 512; k += 256) ws[OFF_EN + k] = 0.f;
    }
}

// -------- kernel 2: act + energy, with rows/dots folded in (4672 blocks) ----
// g < 4096       : act[b,i,j,s,f] bf16 + EN atomics  (needs only stats)
// g in [4096,4160): RS/R2 row sums of proj           (independent)
// g >= 4160      : D dots                            (independent)
__global__ void __launch_bounds__(256)
k_act(const float* __restrict__ x_in, const float* __restrict__ proj,
      const float* __restrict__ sw, const float* __restrict__ omiga,
      float* __restrict__ ws){
    int g = blockIdx.x;
    int t = threadIdx.x;

    if (g < 4096) {
        int bi = g >> 6, sq = g & 63;
        int i = bi & 7;
        int f = t & 63, sl = t >> 6;
        int s = sq*4 + sl;

        __shared__ float swl[8*NC];       // sw[i][j][c]
        __shared__ float om8[8];
        for (int k = t; k < 8*NC; k += 256) swl[k] = sw[i*8*NC + k];
        if (t < 8) om8[t] = fabsf(omiga[i*8 + t]);
        __syncthreads();

        float x = x_in[((size_t)bi*SEQL + s)*FEAT + f];
        float xn = (x - ws[OFF_MU + bi*64 + f]) * ws[OFF_RSTD + bi*64 + f] * 0.5f;
        xn = fminf(fmaxf(xn, -0.99f), 0.99f);
        float u = (xn + 1.f) * 49.f;      // grid uniform: d = |u - c| exactly
        int ic0 = (int)floorf(u) - 1;     // 4-tap support (outside taps = 0)
        float bas[4];
        int   cs[4];
        #pragma unroll
        for (int k = 0; k < 4; ++k) {
            int c = ic0 + k;
            float d = fabsf(u - (float)c);
            float r2 = fmaxf(2.f - d, 0.f);
            float r1 = fmaxf(1.f - d, 0.f);
            float bv = (r2*r2*r2 - 4.f*r1*r1*r1) * (1.f/6.f);
            bool ok = (c >= 0) && (c < NC);
            bas[k] = ok ? bv : 0.f;
            cs[k]  = ok ? c : 0;
        }

        bf16* actp = (bf16*)(ws + OFF_ACT);
        float en[8];
        #pragma unroll
        for (int j = 0; j < 8; ++j) {
            const float* swj = swl + j*NC;
            float sp = bas[0]*swj[cs[0]] + bas[1]*swj[cs[1]]
                     + bas[2]*swj[cs[2]] + bas[3]*swj[cs[3]];
            float a = sp + om8[j] * x;
            en[j] = a * a;
            actp[(((size_t)bi*8 + j)*SEQL + s)*FEAT + f] = __float2bfloat16(a);
        }

        int lane = t & 63, wv = t >> 6;
        #pragma unroll
        for (int o = 32; o > 0; o >>= 1)
            #pragma unroll
            for (int j = 0; j < 8; ++j) en[j] += __shfl_xor(en[j], o);
        __shared__ float red[4][8];
        if (lane == 0)
            #pragma unroll
            for (int j = 0; j < 8; ++j) red[wv][j] = en[j];
        __syncthreads();
        if (t < 8) {
            float tot = red[0][t] + red[1][t] + red[2][t] + red[3][t];
            atomicAdd(&ws[OFF_EN + bi*8 + t], tot);
        }
    } else if (g < 4160) {
        int bi = g - 4096;
        const float4* row = (const float4*)(proj + ((size_t)bi*SEQL + t)*FEAT);
        float s1 = 0.f, s2 = 0.f;
        #pragma unroll
        for (int k = 0; k < 16; ++k) {
            float4 v = row[k];
            s1 += v.x + v.y + v.z + v.w;
            s2 += v.x*v.x + v.y*v.y + v.z*v.z + v.w*v.w;
        }
        ws[OFF_RS + bi*SEQL + t] = s1;
        ws[OFF_R2 + bi*SEQL + t] = s2;
    } else {
        int g2 = g - 4160;                // 512 = bi2*16 + sq
        int bi2 = g2 >> 4, sq = g2 & 15;
        int b = bi2 >> 2, i2 = bi2 & 3;
        __shared__ float PK[16*64];
        const float4* pk = (const float4*)(proj + (((size_t)(b*8 + 2*i2))*SEQL + sq*16)*FEAT);
        ((float4*)PK)[t] = pk[t];
        float4 q[16];
        const float4* pq = (const float4*)(proj + (((size_t)(b*8 + 2*i2 + 1))*SEQL + t)*FEAT);
        #pragma unroll
        for (int k = 0; k < 16; ++k) q[k] = pq[k];
        __syncthreads();
        float* Dp = ws + OFF_D + (((size_t)bi2*SEQL) + sq*16)*SEQL + t;
        for (int s = 0; s < 16; ++s) {
            const float4* kr = (const float4*)(PK + s*64);
            float d = 0.f;
            #pragma unroll
            for (int k = 0; k < 16; ++k) {
                float4 kv = kr[k]; float4 qv = q[k];
                d += kv.x*qv.x + kv.y*qv.y + kv.z*qv.z + kv.w*qv.w;
            }
            Dp[(size_t)s*SEQL] = d;       // t consecutive -> coalesced
        }
    }
}

// mask = sigmoid((es-|tau|)/tv), mult = es/(|tau|+1e-8), es = sqrt(E/16384+1e-8)
__device__ __forceinline__ void mask_mult(float EN, float ta, float tv,
                                          float& mask, float& mult){
    float es = sqrtf(EN * (1.f/16384.f) + 1e-8f);
    mask = 1.f / (1.f + expf(-(es - ta) / tv));
    mult = es / (ta + 1e-8f);
}

// -------- kernel 3: comb = sum_i mk*act; LN; @W2[j]+bs -> x_prime ----------
// grid 2048 = (b*8+j)*32 + sc; 256 thr = 4 waves x 2 s-rows; lane = f  (R9)
__global__ void __launch_bounds__(256)
k_cl2(const float* __restrict__ lnw, const float* __restrict__ lnb,
      const float* __restrict__ W2s, const float* __restrict__ bsb,
      const float* __restrict__ tau, const float* __restrict__ temp,
      float* __restrict__ ws, float* __restrict__ out){
    int g = blockIdx.x;
    int b = g >> 8, j = (g >> 5) & 7, sc = g & 31;
    int t = threadIdx.x;
    int f = t & 63, wv = t >> 6;

    __shared__ float W2l[4096];           // W2s[j] : [f2][f]
    __shared__ float mkj[8];
    __shared__ float xl[4][64];
    {
        const float4* w4 = (const float4*)(W2s + (size_t)j*4096);
        float4* l4 = (float4*)W2l;
        for (int k = t; k < 1024; k += 256) l4[k] = w4[k];
    }
    if (t < 8) {
        float tv = fabsf(temp[0]) + 1e-4f;
        float mk, mu;
        mask_mult(ws[OFF_EN + (b*8 + t)*8 + j], fabsf(tau[t*8 + j]), tv, mk, mu);
        mkj[t] = mk;
    }
    __syncthreads();

    float lnwj = lnw[j*64 + f], lnbj = lnb[j*64 + f];
    const bf16* actp = (const bf16*)(ws + OFF_ACT);

    #pragma unroll
    for (int it = 0; it < 2; ++it) {
        int s = sc*8 + wv*2 + it;
        float comb = 0.f;
        #pragma unroll
        for (int i = 0; i < 8; ++i)
            comb += mkj[i] * b2f(actp[(((size_t)(b*8 + i)*8 + j)*SEQL + s)*FEAT + f]);
        ws[OFF_COMB + (((size_t)(b*8 + j))*SEQL + s)*FEAT + f] = comb;

        float sm_ = comb, sq_ = comb*comb;
        #pragma unroll
        for (int o = 32; o > 0; o >>= 1) { sm_ += __shfl_xor(sm_, o); sq_ += __shfl_xor(sq_, o); }
        float m = sm_ * (1.f/64.f);
        float var = sq_ * (1.f/64.f) - m*m;
        float xnj = (comb - m) * rsqrtf(var + 1e-5f) * lnwj + lnbj;
        xl[wv][f] = xnj;                 // wave-private row: no barrier needed
        float acc = bsb[((size_t)j*SEQL + s)*FEAT + f];
        #pragma unroll 8
        for (int f2 = 0; f2 < 64; ++f2)
            acc += xl[wv][f2] * W2l[f2*64 + f];
        out[OUT1_OFF + (((size_t)(b*8 + j))*SEQL + s)*FEAT + f] = acc;
    }
}

// -------- kernel 4: attention (reads D) + conv + epilogue (R9 version) -----
__global__ void __launch_bounds__(256)
k_attn(const float* __restrict__ temp, const float* __restrict__ convk,
       const float* __restrict__ al, const float* __restrict__ be,
       const float* __restrict__ th, const float* __restrict__ ga,
       const float* __restrict__ tau,
       float* __restrict__ ws, const float* __restrict__ xpo_base,
       float* __restrict__ out){
    int g = blockIdx.x;                   // 2048 = bj*32 + sg
    int bj = g >> 5, sg = g & 31;
    int b = bj >> 3, j = bj & 7;
    int s0 = sg * 8;
    int t = threadIdx.x;                  // 256
    int lane = t & 63, wv = t >> 6;

    __shared__ float wls[8][256];
    __shared__ float part[8][4][64];
    __shared__ float redm[4][8];
    __shared__ float reds[4][8];
    __shared__ float cKs[4], cQs[4], ccs[4];
    __shared__ float mKs[8], iKs[8];

    if (t < 4) {
        int iK = 2*t, iQ = iK + 1;
        float tv = fabsf(temp[0]) + 1e-4f;
        float mk, mu, mq, muq;
        mask_mult(ws[OFF_EN + (b*8 + iK)*8 + j], fabsf(tau[iK*8 + j]), tv, mk, mu);
        mask_mult(ws[OFF_EN + (b*8 + iQ)*8 + j], fabsf(tau[iQ*8 + j]), tv, mq, muq);
        float k_ = mk * mu, q_ = mq * muq;
        cKs[t] = k_; cQs[t] = q_; ccs[t] = k_ * q_;
    }
    __syncthreads();

    // Q-column (t) LN stats
    float mQ = 0.f, e2Q = 0.f;
    #pragma unroll
    for (int i2 = 0; i2 < 4; ++i2) {
        float c = cQs[i2];
        float rs = ws[OFF_RS + (b*8 + 2*i2 + 1)*SEQL + t];
        float r2 = ws[OFF_R2 + (b*8 + 2*i2 + 1)*SEQL + t];
        mQ += c * rs; e2Q += c*c * r2;
    }
    mQ *= (1.f/256.f); e2Q *= (1.f/256.f);
    float iQ = rsqrtf(e2Q - mQ*mQ + 1e-5f);

    if (t < 8) {
        int s = s0 + t;
        float mK = 0.f, e2K = 0.f;
        #pragma unroll
        for (int i2 = 0; i2 < 4; ++i2) {
            float c = cKs[i2];
            float rs = ws[OFF_RS + (b*8 + 2*i2)*SEQL + s];
            float r2 = ws[OFF_R2 + (b*8 + 2*i2)*SEQL + s];
            mK += c * rs; e2K += c*c * r2;
        }
        mK *= (1.f/256.f); e2K *= (1.f/256.f);
        mKs[t] = mK;
        iKs[t] = rsqrtf(e2K - mK*mK + 1e-5f);
    }
    __syncthreads();

    float tv = fabsf(temp[0]) + 1e-4f;
    float rscale = 1.f / (16.f * tv);
    float raw[8];
    #pragma unroll
    for (int r = 0; r < 8; ++r) {
        float d = 0.f;
        #pragma unroll
        for (int i2 = 0; i2 < 4; ++i2)
            d += ccs[i2] * ws[OFF_D + (((size_t)(b*4 + i2))*SEQL + s0 + r)*SEQL + t];
        raw[r] = (d - 256.f*mKs[r]*mQ) * (iKs[r]*iQ) * rscale;
    }

    float mx[8];
    #pragma unroll
    for (int r = 0; r < 8; ++r) mx[r] = raw[r];
    #pragma unroll
    for (int o = 32; o > 0; o >>= 1)
        #pragma unroll
        for (int r = 0; r < 8; ++r) mx[r] = fmaxf(mx[r], __shfl_xor(mx[r], o));
    if (lane == 0)
        #pragma unroll
        for (int r = 0; r < 8; ++r) redm[wv][r] = mx[r];
    __syncthreads();
    float ex[8], sm[8];
    #pragma unroll
    for (int r = 0; r < 8; ++r) {
        float M = fmaxf(fmaxf(redm[0][r], redm[1][r]), fmaxf(redm[2][r], redm[3][r]));
        ex[r] = expf(raw[r] - M);
        sm[r] = ex[r];
    }
    #pragma unroll
    for (int o = 32; o > 0; o >>= 1)
        #pragma unroll
        for (int r = 0; r < 8; ++r) sm[r] += __shfl_xor(sm[r], o);
    if (lane == 0)
        #pragma unroll
        for (int r = 0; r < 8; ++r) reds[wv][r] = sm[r];
    __syncthreads();
    #pragma unroll
    for (int r = 0; r < 8; ++r) {
        float S = reds[0][r] + reds[1][r] + reds[2][r] + reds[3][r];
        wls[r][t] = ex[r] / S;
    }
    __syncthreads();

    const float* xp = xpo_base + (size_t)bj*SEQL*FEAT;       // x_prime (out1)
    const float* cb = ws + OFF_COMB + (size_t)bj*SEQL*FEAT;  // combined f32

    // apply: attn[r][f] = sum_t wls[r][t] * xp[t][f]
    int f = lane, qtr = wv;
    float acc[8] = {0.f,0.f,0.f,0.f,0.f,0.f,0.f,0.f};
    for (int k = 0; k < 64; ++k) {
        int trow = qtr*64 + k;
        float xv = xp[(size_t)trow*FEAT + f];
        #pragma unroll
        for (int r = 0; r < 8; ++r) acc[r] += wls[r][trow] * xv;
    }
    #pragma unroll
    for (int r = 0; r < 8; ++r) part[r][qtr][f] = acc[r];
    __syncthreads();

    // epilogue: all 256 threads, 2 rows each
    {
        float ckf[KS];
        #pragma unroll
        for (int k = 0; k < KS; ++k) ckf[k] = convk[((size_t)j*64 + lane)*KS + k];
        float aa = fabsf(al[j]), ab = fabsf(be[j]);
        float at = fabsf(th[j]), gm = ga[j];
        #pragma unroll
        for (int it = 0; it < 2; ++it) {
            int r = wv*2 + it;
            int s = s0 + r;
            float attn = part[r][0][lane] + part[r][1][lane] + part[r][2][lane] + part[r][3][lane];
            float w3 = 0.f;
            #pragma unroll
            for (int k = 0; k < KS; ++k) {
                int s2 = s + k - 7;
                if (s2 >= 0 && s2 < SEQL) w3 += xp[(size_t)s2*FEAT + lane] * ckf[k];
            }
            float res = ab*attn + aa*xp[(size_t)s*FEAT + lane] + at*w3 + gm*cb[(size_t)s*FEAT + lane];
            out[((size_t)bj*SEQL + s)*FEAT + lane] = res;
        }
    }
}

extern "C" void kernel_launch(void* const* d_in, const int* in_sizes, int n_in,
                              void* d_out, int out_size, void* d_ws, size_t ws_size,
                              hipStream_t stream) {
    const float* x_in  = (const float*)d_in[0];
    const float* proj  = (const float*)d_in[1];
    const float* sw    = (const float*)d_in[3];
    const float* tau   = (const float*)d_in[4];
    const float* temp  = (const float*)d_in[5];
    const float* omiga = (const float*)d_in[6];
    const float* W2s   = (const float*)d_in[7];
    const float* bsb   = (const float*)d_in[8];
    const float* lnw   = (const float*)d_in[9];
    const float* lnb   = (const float*)d_in[10];
    const float* al    = (const float*)d_in[11];
    const float* be    = (const float*)d_in[12];
    const float* th    = (const float*)d_in[13];
    const float* ga    = (const float*)d_in[14];
    const float* ck    = (const float*)d_in[15];
    float* out = (float*)d_out;
    float* ws = (float*)d_ws;

    k_stats<<<64,   256, 0, stream>>>(x_in, ws);
    k_act  <<<4672, 256, 0, stream>>>(x_in, proj, sw, omiga, ws);
    k_cl2  <<<2048, 256, 0, stream>>>(lnw, lnb, W2s, bsb, tau, temp, ws, out);
    k_attn <<<2048, 256, 0, stream>>>(temp, ck, al, be, th, ga, tau, ws,
                                      out + OUT1_OFF, out);
}

// Round 14
// 160.478 us; speedup vs baseline: 1.1296x; 1.1296x over previous
//
#include <hip/hip_runtime.h>
#include <hip/hip_bf16.h>
#include <math.h>

typedef __hip_bfloat16 bf16;
__device__ __forceinline__ float b2f(bf16 v){ return __bfloat162float(v); }

#define SEQL 256
#define FEAT 64
#define NC 99
#define KS 15

// workspace layout in floats (~29.5 MB incl. bf16 act)
#define OFF_MU    0          // 4096    (b,i,f)
#define OFF_RSTD  4096       // 4096
#define OFF_EN    8192       // 512     (b,i,j)  atomic-summed energy
#define OFF_RS    9728       // 16384   (b,i,s)  sum_f proj
#define OFF_R2    26112      // 16384   (b,i,s)  sum_f proj^2
#define OFF_COMB  42496      // 1048576 (b,j,s,f) f32
#define OFF_D     1091072    // 2097152 (b,i2,s,t) f32  j-independent QK dots
#define OFF_ACT   3188224    // 8388608 bf16 slots (b,i,j,s,f)

#define OUT1_OFF  1048576    // projs (x_prime) region start in d_out (f32)

// -------- kernel 1: fused pre-phase (R9 verbatim) --------------------------
// blocks 0..63   : per-(b,i,f) mean/rstd over seq (+ zero EN on block 0)
// blocks 64..127 : row sums of proj (RS, R2)
// blocks 128..639: D[b,i2,s,t] = dot(proj[b,2i2,s,:], proj[b,2i2+1,t,:])
__global__ void __launch_bounds__(256)
k_pre(const float* __restrict__ x_in, const float* __restrict__ proj,
      float* __restrict__ ws){
    int g = blockIdx.x;
    int t = threadIdx.x;

    if (g < 64) {
        int bi = g;
        int f = t & 63, q = t >> 6;
        const float* xp = x_in + (size_t)bi * SEQL * FEAT;
        float s = 0.f, ss = 0.f;
        for (int k = 0; k < 64; ++k) {
            float v = xp[(q*64 + k) * FEAT + f];
            s += v; ss += v * v;
        }
        __shared__ float ls[256], lss[256];
        ls[t] = s; lss[t] = ss;
        __syncthreads();
        if (q == 0) {
            float S  = ls[f]  + ls[64+f]  + ls[128+f]  + ls[192+f];
            float SS = lss[f] + lss[64+f] + lss[128+f] + lss[192+f];
            float m = S * (1.f/256.f);
            float var = SS * (1.f/256.f) - m * m;
            ws[OFF_MU   + bi*64 + f] = m;
            ws[OFF_RSTD + bi*64 + f] = rsqrtf(var + 1e-5f);
        }
        if (bi == 0) {
            for (int k = t; k < 512; k += 256) ws[OFF_EN + k] = 0.f;
        }
    } else if (g < 128) {
        int bi = g - 64;
        const float4* row = (const float4*)(proj + ((size_t)bi*SEQL + t)*FEAT);
        float s1 = 0.f, s2 = 0.f;
        #pragma unroll
        for (int k = 0; k < 16; ++k) {
            float4 v = row[k];
            s1 += v.x + v.y + v.z + v.w;
            s2 += v.x*v.x + v.y*v.y + v.z*v.z + v.w*v.w;
        }
        ws[OFF_RS + bi*SEQL + t] = s1;
        ws[OFF_R2 + bi*SEQL + t] = s2;
    } else {
        int g2 = g - 128;                 // 512 = bi2*16 + sq
        int bi2 = g2 >> 4, sq = g2 & 15;
        int b = bi2 >> 2, i2 = bi2 & 3;
        __shared__ float PK[16*64];
        const float4* pk = (const float4*)(proj + (((size_t)(b*8 + 2*i2))*SEQL + sq*16)*FEAT);
        ((float4*)PK)[t] = pk[t];
        float4 q[16];
        const float4* pq = (const float4*)(proj + (((size_t)(b*8 + 2*i2 + 1))*SEQL + t)*FEAT);
        #pragma unroll
        for (int k = 0; k < 16; ++k) q[k] = pq[k];
        __syncthreads();
        float* Dp = ws + OFF_D + (((size_t)bi2*SEQL) + sq*16)*SEQL + t;
        for (int s = 0; s < 16; ++s) {
            const float4* kr = (const float4*)(PK + s*64);
            float d = 0.f;
            #pragma unroll
            for (int k = 0; k < 16; ++k) {
                float4 kv = kr[k]; float4 qv = q[k];
                d += kv.x*qv.x + kv.y*qv.y + kv.z*qv.z + kv.w*qv.w;
            }
            Dp[(size_t)s*SEQL] = d;       // t consecutive -> coalesced
        }
    }
}

// -------- kernel 2: act[b,i,j,s,f] (bf16) + energy -------------------------
// grid 1024 = bi*16 + sq4; each block does 4 s-tiles (swl loaded once,
// one EN-atomic set) -> 4x fewer waves + 4x fewer LDS preambles vs R9
__global__ void __launch_bounds__(256)
k_act(const float* __restrict__ x_in, const float* __restrict__ sw,
      const float* __restrict__ omiga, float* __restrict__ ws){
    int g = blockIdx.x;
    int bi = g >> 4, sq4 = g & 15;
    int i = bi & 7;
    int t = threadIdx.x;
    int f = t & 63, sl = t >> 6;

    __shared__ float swl[8*NC];           // sw[i][j][c]
    __shared__ float om8[8];
    for (int k = t; k < 8*NC; k += 256) swl[k] = sw[i*8*NC + k];
    if (t < 8) om8[t] = fabsf(omiga[i*8 + t]);
    __syncthreads();

    float mu_f   = ws[OFF_MU   + bi*64 + f];
    float rstd_f = ws[OFF_RSTD + bi*64 + f];
    bf16* actp = (bf16*)(ws + OFF_ACT);
    float en[8] = {0.f,0.f,0.f,0.f,0.f,0.f,0.f,0.f};

    #pragma unroll
    for (int uu = 0; uu < 4; ++uu) {
        int s = (sq4*4 + uu)*4 + sl;
        float x = x_in[((size_t)bi*SEQL + s)*FEAT + f];
        float xn = (x - mu_f) * rstd_f * 0.5f;
        xn = fminf(fmaxf(xn, -0.99f), 0.99f);
        float u = (xn + 1.f) * 49.f;      // grid uniform: d = |u - c| exactly
        int ic0 = (int)floorf(u) - 1;     // 4-tap support (outside taps = 0)
        float bas[4];
        int   cs[4];
        #pragma unroll
        for (int k = 0; k < 4; ++k) {
            int c = ic0 + k;
            float d = fabsf(u - (float)c);
            float r2 = fmaxf(2.f - d, 0.f);
            float r1 = fmaxf(1.f - d, 0.f);
            float bv = (r2*r2*r2 - 4.f*r1*r1*r1) * (1.f/6.f);
            bool ok = (c >= 0) && (c < NC);
            bas[k] = ok ? bv : 0.f;
            cs[k]  = ok ? c : 0;
        }
        #pragma unroll
        for (int j = 0; j < 8; ++j) {
            const float* swj = swl + j*NC;
            float sp = bas[0]*swj[cs[0]] + bas[1]*swj[cs[1]]
                     + bas[2]*swj[cs[2]] + bas[3]*swj[cs[3]];
            float a = sp + om8[j] * x;
            en[j] += a * a;
            actp[(((size_t)bi*8 + j)*SEQL + s)*FEAT + f] = __float2bfloat16(a);
        }
    }

    int lane = t & 63, wv = t >> 6;
    #pragma unroll
    for (int o = 32; o > 0; o >>= 1)
        #pragma unroll
        for (int j = 0; j < 8; ++j) en[j] += __shfl_xor(en[j], o);
    __shared__ float red[4][8];
    if (lane == 0)
        #pragma unroll
        for (int j = 0; j < 8; ++j) red[wv][j] = en[j];
    __syncthreads();
    if (t < 8) {
        float tot = red[0][t] + red[1][t] + red[2][t] + red[3][t];
        atomicAdd(&ws[OFF_EN + bi*8 + t], tot);
    }
}

// mask = sigmoid((es-|tau|)/tv), mult = es/(|tau|+1e-8), es = sqrt(E/16384+1e-8)
__device__ __forceinline__ void mask_mult(float EN, float ta, float tv,
                                          float& mask, float& mult){
    float es = sqrtf(EN * (1.f/16384.f) + 1e-8f);
    mask = 1.f / (1.f + expf(-(es - ta) / tv));
    mult = es / (ta + 1e-8f);
}

// -------- kernel 3: comb = sum_i mk*act; LN; @W2[j]+bs -> x_prime (R9) -----
// grid 2048 = (b*8+j)*32 + sc; 256 thr = 4 waves x 2 s-rows; lane = f
__global__ void __launch_bounds__(256)
k_cl2(const float* __restrict__ lnw, const float* __restrict__ lnb,
      const float* __restrict__ W2s, const float* __restrict__ bsb,
      const float* __restrict__ tau, const float* __restrict__ temp,
      float* __restrict__ ws, float* __restrict__ out){
    int g = blockIdx.x;
    int b = g >> 8, j = (g >> 5) & 7, sc = g & 31;
    int t = threadIdx.x;
    int f = t & 63, wv = t >> 6;

    __shared__ float W2l[4096];           // W2s[j] : [f2][f]
    __shared__ float mkj[8];
    __shared__ float xl[4][64];
    {
        const float4* w4 = (const float4*)(W2s + (size_t)j*4096);
        float4* l4 = (float4*)W2l;
        for (int k = t; k < 1024; k += 256) l4[k] = w4[k];
    }
    if (t < 8) {
        float tv = fabsf(temp[0]) + 1e-4f;
        float mk, mu;
        mask_mult(ws[OFF_EN + (b*8 + t)*8 + j], fabsf(tau[t*8 + j]), tv, mk, mu);
        mkj[t] = mk;
    }
    __syncthreads();

    float lnwj = lnw[j*64 + f], lnbj = lnb[j*64 + f];
    const bf16* actp = (const bf16*)(ws + OFF_ACT);

    #pragma unroll
    for (int it = 0; it < 2; ++it) {
        int s = sc*8 + wv*2 + it;
        float comb = 0.f;
        #pragma unroll
        for (int i = 0; i < 8; ++i)
            comb += mkj[i] * b2f(actp[(((size_t)(b*8 + i)*8 + j)*SEQL + s)*FEAT + f]);
        ws[OFF_COMB + (((size_t)(b*8 + j))*SEQL + s)*FEAT + f] = comb;

        float sm_ = comb, sq_ = comb*comb;
        #pragma unroll
        for (int o = 32; o > 0; o >>= 1) { sm_ += __shfl_xor(sm_, o); sq_ += __shfl_xor(sq_, o); }
        float m = sm_ * (1.f/64.f);
        float var = sq_ * (1.f/64.f) - m*m;
        float xnj = (comb - m) * rsqrtf(var + 1e-5f) * lnwj + lnbj;
        xl[wv][f] = xnj;                 // wave-private row: no barrier needed
        float acc = bsb[((size_t)j*SEQL + s)*FEAT + f];
        #pragma unroll 8
        for (int f2 = 0; f2 < 64; ++f2)
            acc += xl[wv][f2] * W2l[f2*64 + f];
        out[OUT1_OFF + (((size_t)(b*8 + j))*SEQL + s)*FEAT + f] = acc;
    }
}

// -------- kernel 4: attention (reads D) + conv + epilogue (R9 verbatim) ----
__global__ void __launch_bounds__(256)
k_attn(const float* __restrict__ temp, const float* __restrict__ convk,
       const float* __restrict__ al, const float* __restrict__ be,
       const float* __restrict__ th, const float* __restrict__ ga,
       const float* __restrict__ tau,
       float* __restrict__ ws, const float* __restrict__ xpo_base,
       float* __restrict__ out){
    int g = blockIdx.x;                   // 2048 = bj*32 + sg
    int bj = g >> 5, sg = g & 31;
    int b = bj >> 3, j = bj & 7;
    int s0 = sg * 8;
    int t = threadIdx.x;                  // 256
    int lane = t & 63, wv = t >> 6;

    __shared__ float wls[8][256];
    __shared__ float part[8][4][64];
    __shared__ float redm[4][8];
    __shared__ float reds[4][8];
    __shared__ float cKs[4], cQs[4], ccs[4];
    __shared__ float mKs[8], iKs[8];

    if (t < 4) {
        int iK = 2*t, iQ = iK + 1;
        float tv = fabsf(temp[0]) + 1e-4f;
        float mk, mu, mq, muq;
        mask_mult(ws[OFF_EN + (b*8 + iK)*8 + j], fabsf(tau[iK*8 + j]), tv, mk, mu);
        mask_mult(ws[OFF_EN + (b*8 + iQ)*8 + j], fabsf(tau[iQ*8 + j]), tv, mq, muq);
        float k_ = mk * mu, q_ = mq * muq;
        cKs[t] = k_; cQs[t] = q_; ccs[t] = k_ * q_;
    }
    __syncthreads();

    // Q-column (t) LN stats
    float mQ = 0.f, e2Q = 0.f;
    #pragma unroll
    for (int i2 = 0; i2 < 4; ++i2) {
        float c = cQs[i2];
        float rs = ws[OFF_RS + (b*8 + 2*i2 + 1)*SEQL + t];
        float r2 = ws[OFF_R2 + (b*8 + 2*i2 + 1)*SEQL + t];
        mQ += c * rs; e2Q += c*c * r2;
    }
    mQ *= (1.f/256.f); e2Q *= (1.f/256.f);
    float iQ = rsqrtf(e2Q - mQ*mQ + 1e-5f);

    if (t < 8) {
        int s = s0 + t;
        float mK = 0.f, e2K = 0.f;
        #pragma unroll
        for (int i2 = 0; i2 < 4; ++i2) {
            float c = cKs[i2];
            float rs = ws[OFF_RS + (b*8 + 2*i2)*SEQL + s];
            float r2 = ws[OFF_R2 + (b*8 + 2*i2)*SEQL + s];
            mK += c * rs; e2K += c*c * r2;
        }
        mK *= (1.f/256.f); e2K *= (1.f/256.f);
        mKs[t] = mK;
        iKs[t] = rsqrtf(e2K - mK*mK + 1e-5f);
    }
    __syncthreads();

    float tv = fabsf(temp[0]) + 1e-4f;
    float rscale = 1.f / (16.f * tv);
    float raw[8];
    #pragma unroll
    for (int r = 0; r < 8; ++r) {
        float d = 0.f;
        #pragma unroll
        for (int i2 = 0; i2 < 4; ++i2)
            d += ccs[i2] * ws[OFF_D + (((size_t)(b*4 + i2))*SEQL + s0 + r)*SEQL + t];
        raw[r] = (d - 256.f*mKs[r]*mQ) * (iKs[r]*iQ) * rscale;
    }

    float mx[8];
    #pragma unroll
    for (int r = 0; r < 8; ++r) mx[r] = raw[r];
    #pragma unroll
    for (int o = 32; o > 0; o >>= 1)
        #pragma unroll
        for (int r = 0; r < 8; ++r) mx[r] = fmaxf(mx[r], __shfl_xor(mx[r], o));
    if (lane == 0)
        #pragma unroll
        for (int r = 0; r < 8; ++r) redm[wv][r] = mx[r];
    __syncthreads();
    float ex[8], sm[8];
    #pragma unroll
    for (int r = 0; r < 8; ++r) {
        float M = fmaxf(fmaxf(redm[0][r], redm[1][r]), fmaxf(redm[2][r], redm[3][r]));
        ex[r] = expf(raw[r] - M);
        sm[r] = ex[r];
    }
    #pragma unroll
    for (int o = 32; o > 0; o >>= 1)
        #pragma unroll
        for (int r = 0; r < 8; ++r) sm[r] += __shfl_xor(sm[r], o);
    if (lane == 0)
        #pragma unroll
        for (int r = 0; r < 8; ++r) reds[wv][r] = sm[r];
    __syncthreads();
    #pragma unroll
    for (int r = 0; r < 8; ++r) {
        float S = reds[0][r] + reds[1][r] + reds[2][r] + reds[3][r];
        wls[r][t] = ex[r] / S;
    }
    __syncthreads();

    const float* xp = xpo_base + (size_t)bj*SEQL*FEAT;       // x_prime (out1)
    const float* cb = ws + OFF_COMB + (size_t)bj*SEQL*FEAT;  // combined f32

    // apply: attn[r][f] = sum_t wls[r][t] * xp[t][f]
    int f = lane, qtr = wv;
    float acc[8] = {0.f,0.f,0.f,0.f,0.f,0.f,0.f,0.f};
    for (int k = 0; k < 64; ++k) {
        int trow = qtr*64 + k;
        float xv = xp[(size_t)trow*FEAT + f];
        #pragma unroll
        for (int r = 0; r < 8; ++r) acc[r] += wls[r][trow] * xv;
    }
    #pragma unroll
    for (int r = 0; r < 8; ++r) part[r][qtr][f] = acc[r];
    __syncthreads();

    // epilogue: all 256 threads, 2 rows each
    {
        float ckf[KS];
        #pragma unroll
        for (int k = 0; k < KS; ++k) ckf[k] = convk[((size_t)j*64 + lane)*KS + k];
        float aa = fabsf(al[j]), ab = fabsf(be[j]);
        float at = fabsf(th[j]), gm = ga[j];
        #pragma unroll
        for (int it = 0; it < 2; ++it) {
            int r = wv*2 + it;
            int s = s0 + r;
            float attn = part[r][0][lane] + part[r][1][lane] + part[r][2][lane] + part[r][3][lane];
            float w3 = 0.f;
            #pragma unroll
            for (int k = 0; k < KS; ++k) {
                int s2 = s + k - 7;
                if (s2 >= 0 && s2 < SEQL) w3 += xp[(size_t)s2*FEAT + lane] * ckf[k];
            }
            float res = ab*attn + aa*xp[(size_t)s*FEAT + lane] + at*w3 + gm*cb[(size_t)s*FEAT + lane];
            out[((size_t)bj*SEQL + s)*FEAT + lane] = res;
        }
    }
}

extern "C" void kernel_launch(void* const* d_in, const int* in_sizes, int n_in,
                              void* d_out, int out_size, void* d_ws, size_t ws_size,
                              hipStream_t stream) {
    const float* x_in  = (const float*)d_in[0];
    const float* proj  = (const float*)d_in[1];
    const float* sw    = (const float*)d_in[3];
    const float* tau   = (const float*)d_in[4];
    const float* temp  = (const float*)d_in[5];
    const float* omiga = (const float*)d_in[6];
    const float* W2s   = (const float*)d_in[7];
    const float* bsb   = (const float*)d_in[8];
    const float* lnw   = (const float*)d_in[9];
    const float* lnb   = (const float*)d_in[10];
    const float* al    = (const float*)d_in[11];
    const float* be    = (const float*)d_in[12];
    const float* th    = (const float*)d_in[13];
    const float* ga    = (const float*)d_in[14];
    const float* ck    = (const float*)d_in[15];
    float* out = (float*)d_out;
    float* ws = (float*)d_ws;

    k_pre  <<<640,  256, 0, stream>>>(x_in, proj, ws);
    k_act  <<<1024, 256, 0, stream>>>(x_in, sw, omiga, ws);
    k_cl2  <<<2048, 256, 0, stream>>>(lnw, lnb, W2s, bsb, tau, temp, ws, out);
    k_attn <<<2048, 256, 0, stream>>>(temp, ck, al, be, th, ga, tau, ws,
                                      out + OUT1_OFF, out);
}

// Round 15
// 157.686 us; speedup vs baseline: 1.1496x; 1.0177x over previous
//
#include <hip/hip_runtime.h>
#include <hip/hip_bf16.h>
#include <math.h>

typedef __hip_bfloat16 bf16;
__device__ __forceinline__ float b2f(bf16 v){ return __bfloat162float(v); }

#define SEQL 256
#define FEAT 64
#define NC 99
#define KS 15

// workspace layout in floats (~29.5 MB incl. bf16 act)
#define OFF_MU    0          // 4096    (b,i,f)
#define OFF_RSTD  4096       // 4096
#define OFF_EN    8192       // 512     (b,i,j)  atomic-summed energy
#define OFF_RS    9728       // 16384   (b,i,s)  sum_f proj
#define OFF_R2    26112      // 16384   (b,i,s)  sum_f proj^2
#define OFF_COMB  42496      // 1048576 (b,j,s,f) f32
#define OFF_D     1091072    // 2097152 (b,i2,s,t) f32  j-independent QK dots
#define OFF_ACT   3188224    // 8388608 bf16 slots (b,i,j,s,f)

#define OUT1_OFF  1048576    // projs (x_prime) region start in d_out (f32)

// -------- kernel 1: fused pre-phase (R9/R14 verbatim) ----------------------
__global__ void __launch_bounds__(256)
k_pre(const float* __restrict__ x_in, const float* __restrict__ proj,
      float* __restrict__ ws){
    int g = blockIdx.x;
    int t = threadIdx.x;

    if (g < 64) {
        int bi = g;
        int f = t & 63, q = t >> 6;
        const float* xp = x_in + (size_t)bi * SEQL * FEAT;
        float s = 0.f, ss = 0.f;
        for (int k = 0; k < 64; ++k) {
            float v = xp[(q*64 + k) * FEAT + f];
            s += v; ss += v * v;
        }
        __shared__ float ls[256], lss[256];
        ls[t] = s; lss[t] = ss;
        __syncthreads();
        if (q == 0) {
            float S  = ls[f]  + ls[64+f]  + ls[128+f]  + ls[192+f];
            float SS = lss[f] + lss[64+f] + lss[128+f] + lss[192+f];
            float m = S * (1.f/256.f);
            float var = SS * (1.f/256.f) - m * m;
            ws[OFF_MU   + bi*64 + f] = m;
            ws[OFF_RSTD + bi*64 + f] = rsqrtf(var + 1e-5f);
        }
        if (bi == 0) {
            for (int k = t; k < 512; k += 256) ws[OFF_EN + k] = 0.f;
        }
    } else if (g < 128) {
        int bi = g - 64;
        const float4* row = (const float4*)(proj + ((size_t)bi*SEQL + t)*FEAT);
        float s1 = 0.f, s2 = 0.f;
        #pragma unroll
        for (int k = 0; k < 16; ++k) {
            float4 v = row[k];
            s1 += v.x + v.y + v.z + v.w;
            s2 += v.x*v.x + v.y*v.y + v.z*v.z + v.w*v.w;
        }
        ws[OFF_RS + bi*SEQL + t] = s1;
        ws[OFF_R2 + bi*SEQL + t] = s2;
    } else {
        int g2 = g - 128;                 // 512 = bi2*16 + sq
        int bi2 = g2 >> 4, sq = g2 & 15;
        int b = bi2 >> 2, i2 = bi2 & 3;
        __shared__ float PK[16*64];
        const float4* pk = (const float4*)(proj + (((size_t)(b*8 + 2*i2))*SEQL + sq*16)*FEAT);
        ((float4*)PK)[t] = pk[t];
        float4 q[16];
        const float4* pq = (const float4*)(proj + (((size_t)(b*8 + 2*i2 + 1))*SEQL + t)*FEAT);
        #pragma unroll
        for (int k = 0; k < 16; ++k) q[k] = pq[k];
        __syncthreads();
        float* Dp = ws + OFF_D + (((size_t)bi2*SEQL) + sq*16)*SEQL + t;
        for (int s = 0; s < 16; ++s) {
            const float4* kr = (const float4*)(PK + s*64);
            float d = 0.f;
            #pragma unroll
            for (int k = 0; k < 16; ++k) {
                float4 kv = kr[k]; float4 qv = q[k];
                d += kv.x*qv.x + kv.y*qv.y + kv.z*qv.z + kv.w*qv.w;
            }
            Dp[(size_t)s*SEQL] = d;       // t consecutive -> coalesced
        }
    }
}

// -------- kernel 2: act + energy, 4 s-tiles per block (R14 verbatim) -------
__global__ void __launch_bounds__(256)
k_act(const float* __restrict__ x_in, const float* __restrict__ sw,
      const float* __restrict__ omiga, float* __restrict__ ws){
    int g = blockIdx.x;
    int bi = g >> 4, sq4 = g & 15;
    int i = bi & 7;
    int t = threadIdx.x;
    int f = t & 63, sl = t >> 6;

    __shared__ float swl[8*NC];           // sw[i][j][c]
    __shared__ float om8[8];
    for (int k = t; k < 8*NC; k += 256) swl[k] = sw[i*8*NC + k];
    if (t < 8) om8[t] = fabsf(omiga[i*8 + t]);
    __syncthreads();

    float mu_f   = ws[OFF_MU   + bi*64 + f];
    float rstd_f = ws[OFF_RSTD + bi*64 + f];
    bf16* actp = (bf16*)(ws + OFF_ACT);
    float en[8] = {0.f,0.f,0.f,0.f,0.f,0.f,0.f,0.f};

    #pragma unroll
    for (int uu = 0; uu < 4; ++uu) {
        int s = (sq4*4 + uu)*4 + sl;
        float x = x_in[((size_t)bi*SEQL + s)*FEAT + f];
        float xn = (x - mu_f) * rstd_f * 0.5f;
        xn = fminf(fmaxf(xn, -0.99f), 0.99f);
        float u = (xn + 1.f) * 49.f;      // grid uniform: d = |u - c| exactly
        int ic0 = (int)floorf(u) - 1;     // 4-tap support (outside taps = 0)
        float bas[4];
        int   cs[4];
        #pragma unroll
        for (int k = 0; k < 4; ++k) {
            int c = ic0 + k;
            float d = fabsf(u - (float)c);
            float r2 = fmaxf(2.f - d, 0.f);
            float r1 = fmaxf(1.f - d, 0.f);
            float bv = (r2*r2*r2 - 4.f*r1*r1*r1) * (1.f/6.f);
            bool ok = (c >= 0) && (c < NC);
            bas[k] = ok ? bv : 0.f;
            cs[k]  = ok ? c : 0;
        }
        #pragma unroll
        for (int j = 0; j < 8; ++j) {
            const float* swj = swl + j*NC;
            float sp = bas[0]*swj[cs[0]] + bas[1]*swj[cs[1]]
                     + bas[2]*swj[cs[2]] + bas[3]*swj[cs[3]];
            float a = sp + om8[j] * x;
            en[j] += a * a;
            actp[(((size_t)bi*8 + j)*SEQL + s)*FEAT + f] = __float2bfloat16(a);
        }
    }

    int lane = t & 63, wv = t >> 6;
    #pragma unroll
    for (int o = 32; o > 0; o >>= 1)
        #pragma unroll
        for (int j = 0; j < 8; ++j) en[j] += __shfl_xor(en[j], o);
    __shared__ float red[4][8];
    if (lane == 0)
        #pragma unroll
        for (int j = 0; j < 8; ++j) red[wv][j] = en[j];
    __syncthreads();
    if (t < 8) {
        float tot = red[0][t] + red[1][t] + red[2][t] + red[3][t];
        atomicAdd(&ws[OFF_EN + bi*8 + t], tot);
    }
}

// mask = sigmoid((es-|tau|)/tv), mult = es/(|tau|+1e-8), es = sqrt(E/16384+1e-8)
__device__ __forceinline__ void mask_mult(float EN, float ta, float tv,
                                          float& mask, float& mult){
    float es = sqrtf(EN * (1.f/16384.f) + 1e-8f);
    mask = 1.f / (1.f + expf(-(es - ta) / tv));
    mult = es / (ta + 1e-8f);
}

// -------- kernel 3: comb + LN + @W2 + bs -> x_prime (R9/R14 verbatim) ------
__global__ void __launch_bounds__(256)
k_cl2(const float* __restrict__ lnw, const float* __restrict__ lnb,
      const float* __restrict__ W2s, const float* __restrict__ bsb,
      const float* __restrict__ tau, const float* __restrict__ temp,
      float* __restrict__ ws, float* __restrict__ out){
    int g = blockIdx.x;
    int b = g >> 8, j = (g >> 5) & 7, sc = g & 31;
    int t = threadIdx.x;
    int f = t & 63, wv = t >> 6;

    __shared__ float W2l[4096];           // W2s[j] : [f2][f]
    __shared__ float mkj[8];
    __shared__ float xl[4][64];
    {
        const float4* w4 = (const float4*)(W2s + (size_t)j*4096);
        float4* l4 = (float4*)W2l;
        for (int k = t; k < 1024; k += 256) l4[k] = w4[k];
    }
    if (t < 8) {
        float tv = fabsf(temp[0]) + 1e-4f;
        float mk, mu;
        mask_mult(ws[OFF_EN + (b*8 + t)*8 + j], fabsf(tau[t*8 + j]), tv, mk, mu);
        mkj[t] = mk;
    }
    __syncthreads();

    float lnwj = lnw[j*64 + f], lnbj = lnb[j*64 + f];
    const bf16* actp = (const bf16*)(ws + OFF_ACT);

    #pragma unroll
    for (int it = 0; it < 2; ++it) {
        int s = sc*8 + wv*2 + it;
        float comb = 0.f;
        #pragma unroll
        for (int i = 0; i < 8; ++i)
            comb += mkj[i] * b2f(actp[(((size_t)(b*8 + i)*8 + j)*SEQL + s)*FEAT + f]);
        ws[OFF_COMB + (((size_t)(b*8 + j))*SEQL + s)*FEAT + f] = comb;

        float sm_ = comb, sq_ = comb*comb;
        #pragma unroll
        for (int o = 32; o > 0; o >>= 1) { sm_ += __shfl_xor(sm_, o); sq_ += __shfl_xor(sq_, o); }
        float m = sm_ * (1.f/64.f);
        float var = sq_ * (1.f/64.f) - m*m;
        float xnj = (comb - m) * rsqrtf(var + 1e-5f) * lnwj + lnbj;
        xl[wv][f] = xnj;                 // wave-private row: no barrier needed
        float acc = bsb[((size_t)j*SEQL + s)*FEAT + f];
        #pragma unroll 8
        for (int f2 = 0; f2 < 64; ++f2)
            acc += xl[wv][f2] * W2l[f2*64 + f];
        out[OUT1_OFF + (((size_t)(b*8 + j))*SEQL + s)*FEAT + f] = acc;
    }
}

// -------- kernel 4: attention + conv + epilogue (R11 wlsT version) ---------
// softmax weights stored TRANSPOSED wlsT[t*8+r]: apply reads 2x b128
// broadcasts per k instead of 8x b32 -> ~2x fewer LDS issue cycles
__global__ void __launch_bounds__(256)
k_attn(const float* __restrict__ temp, const float* __restrict__ convk,
       const float* __restrict__ al, const float* __restrict__ be,
       const float* __restrict__ th, const float* __restrict__ ga,
       const float* __restrict__ tau,
       float* __restrict__ ws, const float* __restrict__ xpo_base,
       float* __restrict__ out){
    int g = blockIdx.x;                   // 2048 = bj*32 + sg
    int bj = g >> 5, sg = g & 31;
    int b = bj >> 3, j = bj & 7;
    int s0 = sg * 8;
    int t = threadIdx.x;                  // 256
    int lane = t & 63, wv = t >> 6;

    __shared__ float wlsT[256*8];         // [t][r]
    __shared__ float part[8][4][64];
    __shared__ float redm[4][8];
    __shared__ float reds[4][8];
    __shared__ float cKs[4], cQs[4], ccs[4];
    __shared__ float mKs[8], iKs[8];

    if (t < 4) {
        int iK = 2*t, iQ = iK + 1;
        float tv = fabsf(temp[0]) + 1e-4f;
        float mk, mu, mq, muq;
        mask_mult(ws[OFF_EN + (b*8 + iK)*8 + j], fabsf(tau[iK*8 + j]), tv, mk, mu);
        mask_mult(ws[OFF_EN + (b*8 + iQ)*8 + j], fabsf(tau[iQ*8 + j]), tv, mq, muq);
        float k_ = mk * mu, q_ = mq * muq;
        cKs[t] = k_; cQs[t] = q_; ccs[t] = k_ * q_;
    }
    __syncthreads();

    // Q-column (t) LN stats
    float mQ = 0.f, e2Q = 0.f;
    #pragma unroll
    for (int i2 = 0; i2 < 4; ++i2) {
        float c = cQs[i2];
        float rs = ws[OFF_RS + (b*8 + 2*i2 + 1)*SEQL + t];
        float r2 = ws[OFF_R2 + (b*8 + 2*i2 + 1)*SEQL + t];
        mQ += c * rs; e2Q += c*c * r2;
    }
    mQ *= (1.f/256.f); e2Q *= (1.f/256.f);
    float iQ = rsqrtf(e2Q - mQ*mQ + 1e-5f);

    if (t < 8) {
        int s = s0 + t;
        float mK = 0.f, e2K = 0.f;
        #pragma unroll
        for (int i2 = 0; i2 < 4; ++i2) {
            float c = cKs[i2];
            float rs = ws[OFF_RS + (b*8 + 2*i2)*SEQL + s];
            float r2 = ws[OFF_R2 + (b*8 + 2*i2)*SEQL + s];
            mK += c * rs; e2K += c*c * r2;
        }
        mK *= (1.f/256.f); e2K *= (1.f/256.f);
        mKs[t] = mK;
        iKs[t] = rsqrtf(e2K - mK*mK + 1e-5f);
    }
    __syncthreads();

    float tv = fabsf(temp[0]) + 1e-4f;
    float rscale = 1.f / (16.f * tv);
    float raw[8];
    #pragma unroll
    for (int r = 0; r < 8; ++r) {
        float d = 0.f;
        #pragma unroll
        for (int i2 = 0; i2 < 4; ++i2)
            d += ccs[i2] * ws[OFF_D + (((size_t)(b*4 + i2))*SEQL + s0 + r)*SEQL + t];
        raw[r] = (d - 256.f*mKs[r]*mQ) * (iKs[r]*iQ) * rscale;
    }

    float mx[8];
    #pragma unroll
    for (int r = 0; r < 8; ++r) mx[r] = raw[r];
    #pragma unroll
    for (int o = 32; o > 0; o >>= 1)
        #pragma unroll
        for (int r = 0; r < 8; ++r) mx[r] = fmaxf(mx[r], __shfl_xor(mx[r], o));
    if (lane == 0)
        #pragma unroll
        for (int r = 0; r < 8; ++r) redm[wv][r] = mx[r];
    __syncthreads();
    float ex[8], sm[8];
    #pragma unroll
    for (int r = 0; r < 8; ++r) {
        float M = fmaxf(fmaxf(redm[0][r], redm[1][r]), fmaxf(redm[2][r], redm[3][r]));
        ex[r] = expf(raw[r] - M);
        sm[r] = ex[r];
    }
    #pragma unroll
    for (int o = 32; o > 0; o >>= 1)
        #pragma unroll
        for (int r = 0; r < 8; ++r) sm[r] += __shfl_xor(sm[r], o);
    if (lane == 0)
        #pragma unroll
        for (int r = 0; r < 8; ++r) reds[wv][r] = sm[r];
    __syncthreads();
    {
        float4 w0, w1;
        float S0 = reds[0][0]+reds[1][0]+reds[2][0]+reds[3][0];
        float S1 = reds[0][1]+reds[1][1]+reds[2][1]+reds[3][1];
        float S2 = reds[0][2]+reds[1][2]+reds[2][2]+reds[3][2];
        float S3 = reds[0][3]+reds[1][3]+reds[2][3]+reds[3][3];
        float S4 = reds[0][4]+reds[1][4]+reds[2][4]+reds[3][4];
        float S5 = reds[0][5]+reds[1][5]+reds[2][5]+reds[3][5];
        float S6 = reds[0][6]+reds[1][6]+reds[2][6]+reds[3][6];
        float S7 = reds[0][7]+reds[1][7]+reds[2][7]+reds[3][7];
        w0.x = ex[0]/S0; w0.y = ex[1]/S1; w0.z = ex[2]/S2; w0.w = ex[3]/S3;
        w1.x = ex[4]/S4; w1.y = ex[5]/S5; w1.z = ex[6]/S6; w1.w = ex[7]/S7;
        float4* wt4 = (float4*)wlsT;
        wt4[t*2]   = w0;
        wt4[t*2+1] = w1;
    }
    __syncthreads();

    const float* xp = xpo_base + (size_t)bj*SEQL*FEAT;       // x_prime (out1)
    const float* cb = ws + OFF_COMB + (size_t)bj*SEQL*FEAT;  // combined f32

    // apply: attn[r][f] = sum_t wlsT[t][r] * xp[t][f]
    int f = lane, qtr = wv;
    float acc[8] = {0.f,0.f,0.f,0.f,0.f,0.f,0.f,0.f};
    const float4* wt4 = (const float4*)wlsT;
    for (int k = 0; k < 64; ++k) {
        int trow = qtr*64 + k;
        float xv = xp[(size_t)trow*FEAT + f];
        float4 w0 = wt4[trow*2];          // broadcast b128 (same addr all lanes)
        float4 w1 = wt4[trow*2+1];
        acc[0] += w0.x*xv; acc[1] += w0.y*xv; acc[2] += w0.z*xv; acc[3] += w0.w*xv;
        acc[4] += w1.x*xv; acc[5] += w1.y*xv; acc[6] += w1.z*xv; acc[7] += w1.w*xv;
    }
    #pragma unroll
    for (int r = 0; r < 8; ++r) part[r][qtr][f] = acc[r];
    __syncthreads();

    // epilogue: all 256 threads, 2 rows each
    {
        float ckf[KS];
        #pragma unroll
        for (int k = 0; k < KS; ++k) ckf[k] = convk[((size_t)j*64 + lane)*KS + k];
        float aa = fabsf(al[j]), ab = fabsf(be[j]);
        float at = fabsf(th[j]), gm = ga[j];
        #pragma unroll
        for (int it = 0; it < 2; ++it) {
            int r = wv*2 + it;
            int s = s0 + r;
            float attn = part[r][0][lane] + part[r][1][lane] + part[r][2][lane] + part[r][3][lane];
            float w3 = 0.f;
            #pragma unroll
            for (int k = 0; k < KS; ++k) {
                int s2 = s + k - 7;
                if (s2 >= 0 && s2 < SEQL) w3 += xp[(size_t)s2*FEAT + lane] * ckf[k];
            }
            float res = ab*attn + aa*xp[(size_t)s*FEAT + lane] + at*w3 + gm*cb[(size_t)s*FEAT + lane];
            out[((size_t)bj*SEQL + s)*FEAT + lane] = res;
        }
    }
}

extern "C" void kernel_launch(void* const* d_in, const int* in_sizes, int n_in,
                              void* d_out, int out_size, void* d_ws, size_t ws_size,
                              hipStream_t stream) {
    const float* x_in  = (const float*)d_in[0];
    const float* proj  = (const float*)d_in[1];
    const float* sw    = (const float*)d_in[3];
    const float* tau   = (const float*)d_in[4];
    const float* temp  = (const float*)d_in[5];
    const float* omiga = (const float*)d_in[6];
    const float* W2s   = (const float*)d_in[7];
    const float* bsb   = (const float*)d_in[8];
    const float* lnw   = (const float*)d_in[9];
    const float* lnb   = (const float*)d_in[10];
    const float* al    = (const float*)d_in[11];
    const float* be    = (const float*)d_in[12];
    const float* th    = (const float*)d_in[13];
    const float* ga    = (const float*)d_in[14];
    const float* ck    = (const float*)d_in[15];
    float* out = (float*)d_out;
    float* ws = (float*)d_ws;

    k_pre  <<<640,  256, 0, stream>>>(x_in, proj, ws);
    k_act  <<<1024, 256, 0, stream>>>(x_in, sw, omiga, ws);
    k_cl2  <<<2048, 256, 0, stream>>>(lnw, lnb, W2s, bsb, tau, temp, ws, out);
    k_attn <<<2048, 256, 0, stream>>>(temp, ck, al, be, th, ga, tau, ws,
                                      out + OUT1_OFF, out);
}